// Round 8
// baseline (119.065 us; speedup 1.0000x reference)
//
#include <hip/hip_runtime.h>
#include <hip/hip_bf16.h>

#define Tt 512
#define Bb 512
#define DV 256
#define DQ 128
#define DH 64
#define CTXN (Tt * DV)  // 131072 floats: context part of d_out
#define TW 64           // t-rows per block
#define BCH 8           // b's per block (sequential)
#define NCH (Bb / BCH)  // 64 chunks

typedef __attribute__((ext_vector_type(8))) short bf16x8;
typedef __attribute__((ext_vector_type(4))) float f32x4;

__device__ __forceinline__ unsigned short f2bf(float x) {
  unsigned u = __float_as_uint(x);
  u += 0x7FFFu + ((u >> 16) & 1u);   // RNE
  return (unsigned short)(u >> 16);
}

// ---- Kernel 0: prep. blocks 0..511: qh[b,h]; blocks 512..575: W1 -> bf16 ----
__global__ void prep_kernel(const float* __restrict__ query,
                            const float* __restrict__ W1,
                            const float* __restrict__ W2,
                            const float* __restrict__ b1,
                            const float* __restrict__ b2,
                            float* __restrict__ qh,
                            unsigned short* __restrict__ w1bf) {
  __shared__ float q[DQ];
  const int blk = blockIdx.x;
  const int h = threadIdx.x;     // 64
  if (blk < Bb) {
    q[h]      = query[blk * DQ + h];
    q[h + 64] = query[blk * DQ + h + 64];
    __syncthreads();
    const float* w2r = W2 + h * DQ;
    float acc = 0.f;
#pragma unroll 8
    for (int k = 0; k < DQ; ++k) acc = fmaf(w2r[k], q[k], acc);
    qh[blk * DH + h] = acc + b1[h] + b2[h];
  } else {
    int base = (blk - Bb) * 256;
#pragma unroll
    for (int k = 0; k < 4; ++k) {
      int i = base + (k << 6) + h;
      w1bf[i] = f2bf(W1[i]);
    }
  }
}

// ---- Kernel 1: FUSED single HBM pass, barrier-free main loop ----
// grid 512 = (t-window 0..7) x (chunk 0..63). Block 256 thr = 4 waves.
// Wave wv owns t-rows t0+wv*16..+15 for ALL 8 b's (processed sequentially).
// Per b: GEMM (M=16,N=64,K=256, A direct global->bf16) -> tanh -> Wv-dot ->
// e^s (no max: |s| <= sum|Wv|+|bv| <= 8.125), broadcast w to each row-lane,
// then lane accumulates num[v-slice] += w * v (f32 re-read, L1/L2-hot, same
// addresses as the GEMM loads) into PRIVATE registers. Disjoint ownership ->
// no barriers, no atomics. Partials out at block end.
__global__ __launch_bounds__(256, 2) void fused3_kernel(
    const float* __restrict__ values,
    const unsigned short* __restrict__ w1bf,
    const float* __restrict__ qh,
    const float* __restrict__ Wv,
    const float* __restrict__ bv,
    float* __restrict__ es,       // [Bb][Tt]
    float* __restrict__ num_p,    // [NCH][Tt][DV]
    float* __restrict__ den_p) {  // [NCH][Tt]
  __shared__ __align__(16) unsigned short lB[DH * DV];  // 32 KB swizzled W1
  __shared__ float lQh[BCH * DH];                       // 2 KB
  const int tid = threadIdx.x;
  const int chunk = blockIdx.x & (NCH - 1);
  const int t0 = (blockIdx.x >> 6) * TW;
  const int b0 = chunk * BCH;

  // stage W1 bf16 -> lB, XOR-swizzle byte ^= (row&7)<<4
  const uint4* w1v = (const uint4*)w1bf;
#pragma unroll
  for (int i = 0; i < 8; ++i) {
    int vec = i * 256 + tid;
    uint4 d = w1v[vec];
    int row = vec >> 5;
    int u = vec & 31;
    int byte = (row << 9) + (u << 4);
    *(uint4*)((char*)lB + (byte ^ ((row & 7) << 4))) = d;
  }
  lQh[tid]       = qh[b0 * DH + tid];
  lQh[tid + 256] = qh[b0 * DH + tid + 256];
  __syncthreads();

  const int wv = tid >> 6, lane = tid & 63;
  const int lrow = lane & 15, g = lane >> 4;
  const int arow = wv * 16 + lrow;      // wave-local t-row (fixed across b)

  float wvc[4];
#pragma unroll
  for (int nt = 0; nt < 4; ++nt) wvc[nt] = Wv[nt * 16 + lrow];
  const float bv0 = bv[0];

  float num[8][8];   // [ks][e] : v = ks*32 + g*8 + e  (lane-private, 64 VGPR)
#pragma unroll
  for (int ks = 0; ks < 8; ++ks)
#pragma unroll
    for (int e = 0; e < 8; ++e) num[ks][e] = 0.f;
  float den = 0.f;

#pragma unroll 1
  for (int bi = 0; bi < BCH; ++bi) {
    const int b = b0 + bi;
    const float* ap = values + ((size_t)b * Tt + t0 + arow) * DV + g * 8;

    // GEMM: A fragments transient per ks (no big register state)
    f32x4 acc[4];
#pragma unroll
    for (int nt = 0; nt < 4; ++nt) acc[nt] = (f32x4){0.f, 0.f, 0.f, 0.f};
#pragma unroll
    for (int ks = 0; ks < 8; ++ks) {
      float4 f0 = *(const float4*)(ap + ks * 32);
      float4 f1 = *(const float4*)(ap + ks * 32 + 4);
      bf16x8 af;
      af[0] = (short)f2bf(f0.x); af[1] = (short)f2bf(f0.y);
      af[2] = (short)f2bf(f0.z); af[3] = (short)f2bf(f0.w);
      af[4] = (short)f2bf(f1.x); af[5] = (short)f2bf(f1.y);
      af[6] = (short)f2bf(f1.z); af[7] = (short)f2bf(f1.w);
      int k2 = (ks * 32 + g * 8) * 2;
#pragma unroll
      for (int nt = 0; nt < 4; ++nt) {
        int brow = nt * 16 + lrow;
        bf16x8 bf = *(const bf16x8*)((const char*)lB +
                                     (((brow << 9) + k2) ^ ((brow & 7) << 4)));
        acc[nt] = __builtin_amdgcn_mfma_f32_16x16x32_bf16(af, bf, acc[nt], 0, 0, 0);
      }
    }

    // epilogue: +qh, tanh, *Wv, 16-lane reduce -> e^s for rows g*4+j (verified r5)
    const float* qrow = lQh + bi * DH;
    float sc[4] = {0.f, 0.f, 0.f, 0.f};
#pragma unroll
    for (int nt = 0; nt < 4; ++nt) {
      float qv = qrow[nt * 16 + lrow];
#pragma unroll
      for (int j = 0; j < 4; ++j) {
        float hv = acc[nt][j] + qv;
        float e2 = __expf(2.f * hv);
        float th = (e2 - 1.f) / (e2 + 1.f);
        sc[j] = fmaf(th, wvc[nt], sc[j]);
      }
    }
#pragma unroll
    for (int j = 0; j < 4; ++j) {
      float v = sc[j];
      v += __shfl_xor(v, 1);
      v += __shfl_xor(v, 2);
      v += __shfl_xor(v, 4);
      v += __shfl_xor(v, 8);
      sc[j] = __expf(v + bv0);   // e^s for wave-local row g*4+j
    }
    if (lrow == 0) {
#pragma unroll
      for (int j = 0; j < 4; ++j)
        es[(size_t)b * Tt + t0 + wv * 16 + g * 4 + j] = sc[j];
    }
    // broadcast: lane needs w for ITS row (local row lrow), held at group
    // lrow>>2 (lane (lrow>>2)*16), register index lrow&3  (verified round 5)
    int src = (lrow >> 2) << 4;
    float w0 = __shfl(sc[0], src), w1 = __shfl(sc[1], src);
    float w2 = __shfl(sc[2], src), w3 = __shfl(sc[3], src);
    int jm = lrow & 3;
    float w = (jm == 0) ? w0 : (jm == 1) ? w1 : (jm == 2) ? w2 : w3;
    den += w;
    // accumulate num += w * v, re-reading f32 values (cache-hot, loads
    // independent of w -> compiler hoists them over the epilogue)
#pragma unroll
    for (int ks = 0; ks < 8; ++ks) {
      float4 v0 = *(const float4*)(ap + ks * 32);
      float4 v1 = *(const float4*)(ap + ks * 32 + 4);
      num[ks][0] = fmaf(w, v0.x, num[ks][0]);
      num[ks][1] = fmaf(w, v0.y, num[ks][1]);
      num[ks][2] = fmaf(w, v0.z, num[ks][2]);
      num[ks][3] = fmaf(w, v0.w, num[ks][3]);
      num[ks][4] = fmaf(w, v1.x, num[ks][4]);
      num[ks][5] = fmaf(w, v1.y, num[ks][5]);
      num[ks][6] = fmaf(w, v1.z, num[ks][6]);
      num[ks][7] = fmaf(w, v1.w, num[ks][7]);
    }
  }

  // write partials: num_p[chunk][t0+arow][ks*32+g*8 ..], den_p[chunk][t0+arow]
  float* np = num_p + ((size_t)chunk * Tt + t0 + arow) * DV + g * 8;
#pragma unroll
  for (int ks = 0; ks < 8; ++ks) {
    *(float4*)(np + ks * 32) =
        make_float4(num[ks][0], num[ks][1], num[ks][2], num[ks][3]);
    *(float4*)(np + ks * 32 + 4) =
        make_float4(num[ks][4], num[ks][5], num[ks][6], num[ks][7]);
  }
  if (g == 0) den_p[chunk * Tt + t0 + arow] = den;
}

// ---- Kernel 2: combine partials -> context[t,:], and Z[t] ----
__global__ __launch_bounds__(256) void fin_ctx_kernel(
    const float* __restrict__ num_p, const float* __restrict__ den_p,
    float* __restrict__ Zbuf, float* __restrict__ out) {
  const int t = blockIdx.x;
  const int tid = threadIdx.x;
  float Z = 0.f;
#pragma unroll 16
  for (int c = 0; c < NCH; ++c) Z += den_p[c * Tt + t];
  float s = 0.f;
#pragma unroll 8
  for (int c = 0; c < NCH; ++c)
    s += num_p[((size_t)c * Tt + t) * DV + tid];
  out[t * DV + tid] = s / Z;
  if (tid == 0) Zbuf[t] = Z;
}

// ---- Kernel 3: weights[b,t] = e^s / Z[t] ----
__global__ __launch_bounds__(256) void fin_w_kernel(
    const float* __restrict__ es, const float* __restrict__ Zbuf,
    float* __restrict__ out) {
  const int b = blockIdx.x;
  const int tid = threadIdx.x;
#pragma unroll
  for (int i = 0; i < 2; ++i) {
    int t = i * 256 + tid;
    out[CTXN + b * Tt + t] = es[(size_t)b * Tt + t] / Zbuf[t];
  }
}

extern "C" void kernel_launch(void* const* d_in, const int* in_sizes, int n_in,
                              void* d_out, int out_size, void* d_ws, size_t ws_size,
                              hipStream_t stream) {
  const float* query  = (const float*)d_in[0];
  const float* values = (const float*)d_in[1];
  const float* W1     = (const float*)d_in[2];
  const float* b1     = (const float*)d_in[3];
  const float* W2     = (const float*)d_in[4];
  const float* b2     = (const float*)d_in[5];
  const float* Wv     = (const float*)d_in[6];
  const float* bv     = (const float*)d_in[7];
  float* out = (float*)d_out;
  char* ws = (char*)d_ws;
  float* qh            = (float*)ws;                       // 128 KiB
  unsigned short* w1bf = (unsigned short*)(ws + 131072);   //  32 KiB
  float* es            = (float*)(ws + 163840);            //   1 MiB
  float* den_p         = (float*)(ws + 1212416);           // 128 KiB
  float* Zbuf          = (float*)(ws + 1343488);           //   2 KiB
  float* num_p         = (float*)(ws + 1345536);           //  32 MiB

  prep_kernel<<<dim3(Bb + 64), dim3(64), 0, stream>>>(query, W1, W2, b1, b2, qh, w1bf);
  fused3_kernel<<<dim3(512), dim3(256), 0, stream>>>(values, w1bf, qh, Wv, bv,
                                                     es, num_p, den_p);
  fin_ctx_kernel<<<dim3(Tt), dim3(256), 0, stream>>>(num_p, den_p, Zbuf, out);
  fin_w_kernel<<<dim3(Bb), dim3(256), 0, stream>>>(es, Zbuf, out);
}